// Round 8
// baseline (334.749 us; speedup 1.0000x reference)
//
#include <hip/hip_runtime.h>
#include <cstddef>
#include <cstdint>

#define CCH 256   // channels
#define DQK 32    // q/k channels
#define NPX 4096  // H*W
#define QW  16    // queries per wave
#define BM  64    // key tile per iteration
#define NB  4     // batch

typedef __attribute__((ext_vector_type(8))) short bf16x8;   // 8 bf16 = 4 VGPR (MFMA A/B frag)
typedef __attribute__((ext_vector_type(4))) float f32x4;    // MFMA C/D frag
typedef __attribute__((ext_vector_type(4))) unsigned int u32x4;

__device__ inline unsigned short f2bf(float f) {            // RNE float->bf16
    unsigned u = __builtin_bit_cast(unsigned, f);
    u += 0x7FFFu + ((u >> 16) & 1u);
    return (unsigned short)(u >> 16);
}
__device__ inline float bf2f(unsigned short h) {
    unsigned u = (unsigned)h << 16;
    return __builtin_bit_cast(float, u);
}

// ---------------------------------------------------------------------------
// Fused q/k/v 1x1-conv projection -> bf16 outputs in ws (unchanged, works).
//   qT: [NB][NPX][32], kT: [NB][NPX][32], v: [NB][CCH][NPX]
// ---------------------------------------------------------------------------
__global__ __launch_bounds__(256) void proj_kernel(
    const float* __restrict__ x,
    const float* __restrict__ Wq, const float* __restrict__ bq,
    const float* __restrict__ Wk, const float* __restrict__ bk,
    const float* __restrict__ Wv, const float* __restrict__ bv,
    unsigned short* __restrict__ ws)
{
    const int tid = threadIdx.x;
    const int b   = blockIdx.z;
    const int o0  = blockIdx.y * 16;
    const int nb  = blockIdx.x * 1024 + tid * 4;

    const float* Wbase;
    const float* bbase;
    if (o0 < 32)      { Wbase = Wq + o0 * CCH;        bbase = bq + o0; }
    else if (o0 < 64) { Wbase = Wk + (o0 - 32) * CCH; bbase = bk + (o0 - 32); }
    else              { Wbase = Wv + (o0 - 64) * CCH; bbase = bv + (o0 - 64); }

    float4 acc[16];
#pragma unroll
    for (int ol = 0; ol < 16; ++ol) {
        float bb = bbase[ol];
        acc[ol] = make_float4(bb, bb, bb, bb);
    }

    const float* xp = x + ((size_t)b * CCH) * NPX + nb;
#pragma unroll 4
    for (int c = 0; c < CCH; ++c) {
        float4 x4 = *(const float4*)(xp + (size_t)c * NPX);
#pragma unroll
        for (int ol = 0; ol < 16; ++ol) {
            float w = Wbase[ol * CCH + c];
            acc[ol].x += w * x4.x;
            acc[ol].y += w * x4.y;
            acc[ol].z += w * x4.z;
            acc[ol].w += w * x4.w;
        }
    }

    if (o0 < 64) {
        unsigned short* dstT = ws + ((o0 < 32) ? (size_t)0 : (size_t)NB * NPX * 32);
        const int col0 = o0 & 16;
        unsigned short* base = dstT + ((size_t)b * NPX + nb) * 32 + col0;
#pragma unroll
        for (int p = 0; p < 4; ++p) {
            unsigned u[8];
#pragma unroll
            for (int h = 0; h < 8; ++h) {
                const float* a0 = (const float*)&acc[2 * h];
                const float* a1 = (const float*)&acc[2 * h + 1];
                u[h] = (unsigned)f2bf(a0[p]) | ((unsigned)f2bf(a1[p]) << 16);
            }
            u32x4* dp = (u32x4*)(base + (size_t)p * 32);
            dp[0] = (u32x4){u[0], u[1], u[2], u[3]};
            dp[1] = (u32x4){u[4], u[5], u[6], u[7]};
        }
    } else {
        unsigned short* vbase = ws + (size_t)2 * NB * NPX * 32;
        const int c0 = o0 - 64;
#pragma unroll
        for (int ol = 0; ol < 16; ++ol) {
            unsigned lo = (unsigned)f2bf(acc[ol].x) | ((unsigned)f2bf(acc[ol].y) << 16);
            unsigned hi = (unsigned)f2bf(acc[ol].z) | ((unsigned)f2bf(acc[ol].w) << 16);
            uint2* dp = (uint2*)(vbase + ((size_t)(b * CCH + c0 + ol)) * NPX + nb);
            *dp = make_uint2(lo, hi);
        }
    }
}

// ---------------------------------------------------------------------------
// Barrier-free flash attention: each WAVE owns one 16-query tile x one key
// slice, all 256 channels. Softmax fully in-register (per-lane m/l for q=ln,
// replicated over the four 16-lane groups). P goes through a wave-PRIVATE
// 2KB LDS patch (XOR-swizzled) -- same-wave ds_write/ds_read, lgkmcnt only,
// ZERO __syncthreads. Block = 4 independent waves.
// Job decode: batch pinned to XCD pair via bid&7; jb=(tile,slice).
// ---------------------------------------------------------------------------
__global__ __launch_bounds__(256, 4) void attn_kernel(
    const unsigned short* __restrict__ qT, const unsigned short* __restrict__ kT,
    const unsigned short* __restrict__ vB, const float* __restrict__ x,
    const float* __restrict__ gamma, float* __restrict__ out,
    unsigned short* __restrict__ opart, float* __restrict__ mlm,
    float* __restrict__ mll, int ns)
{
    __shared__ __align__(16) unsigned short Pl[4][QW * BM];   // 2KB per wave

    const int tid  = threadIdx.x;
    const int lane = tid & 63;
    const int w    = tid >> 6;
    const int ln   = lane & 15;
    const int g    = lane >> 4;      // 16-lane group 0..3
    const int bid  = blockIdx.x;

    const int b    = (bid & 7) >> 1;                       // batch -> XCD pair
    const int jb   = ((bid >> 3) * 2 + (bid & 1)) * 4 + w; // wave-job in batch
    const int tile = jb / ns;
    const int s    = jb - tile * ns;
    const int n0   = tile * QW;

    char* const plb = (char*)&Pl[w][0];                    // wave-private P

    // q B-frag: qT[n0+ln][8g..8g+7]
    const bf16x8 qf = *(const bf16x8*)(qT + ((size_t)b * NPX + n0 + ln) * 32 + g * 8);

    f32x4 acc[16];
#pragma unroll
    for (int ct = 0; ct < 16; ++ct) acc[ct] = (f32x4){0.f, 0.f, 0.f, 0.f};
    float mreg = -INFINITY, lreg = 0.f;

    const unsigned short* kTb = kT + (size_t)b * NPX * 32;
    const unsigned short* vb  = vB + (size_t)b * CCH * NPX;
    const int kbase = s * (NPX / ns);
    const int iters = NPX / (ns * BM);
    const unsigned swz = ((unsigned)ln & 7u) << 4;
    const unsigned rowb = (unsigned)ln * 128u;

    for (int mb = 0; mb < iters; ++mb) {
        const int m0 = kbase + mb * BM;

        // ---- E: 4 MFMA -> lane holds E[q=ln][k=16*s4+4g+reg]
        f32x4 e[4];
#pragma unroll
        for (int s4 = 0; s4 < 4; ++s4) {
            const bf16x8 ka = *(const bf16x8*)(kTb + (size_t)(m0 + s4 * 16 + ln) * 32 + g * 8);
            e[s4] = __builtin_amdgcn_mfma_f32_16x16x32_bf16(
                        ka, qf, (f32x4){0.f, 0.f, 0.f, 0.f}, 0, 0, 0);
        }

        // ---- in-register online softmax for row q=ln (64 keys)
        float lm = -INFINITY;
#pragma unroll
        for (int s4 = 0; s4 < 4; ++s4)
#pragma unroll
            for (int rr = 0; rr < 4; ++rr) lm = fmaxf(lm, e[s4][rr]);
        lm = fmaxf(lm, __shfl_xor(lm, 16));
        lm = fmaxf(lm, __shfl_xor(lm, 32));
        const float mnew = fmaxf(mreg, lm);
        const float sc   = __expf(mreg - mnew);   // first iter: exp(-inf)=0
        float ps = 0.f;
#pragma unroll
        for (int s4 = 0; s4 < 4; ++s4)
#pragma unroll
            for (int rr = 0; rr < 4; ++rr) {
                const float p = __expf(e[s4][rr] - mnew);
                e[s4][rr] = p;
                ps += p;
            }
        ps += __shfl_xor(ps, 16);
        ps += __shfl_xor(ps, 32);
        lreg = lreg * sc + ps;
        mreg = mnew;

        // ---- rescale accumulators
#pragma unroll
        for (int ct = 0; ct < 16; ++ct)
#pragma unroll
            for (int rr = 0; rr < 4; ++rr) acc[ct][rr] *= sc;

        // ---- P -> wave-private LDS (bf16, XOR-swizzled rows of 128B)
#pragma unroll
        for (int s4 = 0; s4 < 4; ++s4) {
            uint2 pk;
            pk.x = (unsigned)f2bf(e[s4][0]) | ((unsigned)f2bf(e[s4][1]) << 16);
            pk.y = (unsigned)f2bf(e[s4][2]) | ((unsigned)f2bf(e[s4][3]) << 16);
            *(uint2*)(plb + rowb + (((unsigned)(s4 * 32 + g * 8)) ^ swz)) = pk;
        }
        // ---- P B-frags: lane needs P[q=ln][32*kc + 8g + i]
        const bf16x8 pf0 = *(const bf16x8*)(plb + rowb + (((unsigned)(g * 16))      ^ swz));
        const bf16x8 pf1 = *(const bf16x8*)(plb + rowb + (((unsigned)(64 + g * 16)) ^ swz));

        // ---- PV: 16 c-tiles x 2 k-chunks
#pragma unroll
        for (int ct = 0; ct < 16; ++ct) {
            const unsigned short* vrow = vb + (size_t)(ct * 16 + ln) * NPX + m0 + g * 8;
            const bf16x8 va0 = *(const bf16x8*)(vrow);        // keys m0+8g+i
            const bf16x8 va1 = *(const bf16x8*)(vrow + 32);   // keys m0+32+8g+i
            acc[ct] = __builtin_amdgcn_mfma_f32_16x16x32_bf16(va0, pf0, acc[ct], 0, 0, 0);
            acc[ct] = __builtin_amdgcn_mfma_f32_16x16x32_bf16(va1, pf1, acc[ct], 0, 0, 0);
        }
    }

    if (opart) {
        // partial epilogue: raw acc (bf16) + per-query m,l
        const size_t sb = (size_t)(s * NB + b);
#pragma unroll
        for (int ct = 0; ct < 16; ++ct) {
            const size_t c0 = sb * CCH + ct * 16 + g * 4;
#pragma unroll
            for (int rr = 0; rr < 4; ++rr)
                opart[(c0 + rr) * NPX + n0 + ln] = f2bf(acc[ct][rr]);
        }
        if (g == 0) {
            mlm[sb * NPX + n0 + ln] = mreg;
            mll[sb * NPX + n0 + ln] = lreg;
        }
    } else {
        // direct epilogue (ns==1 fallback)
        const float gm = gamma[0];
        const float iv = 1.f / lreg;
#pragma unroll
        for (int ct = 0; ct < 16; ++ct) {
            const size_t c0 = (size_t)b * CCH + ct * 16 + g * 4;
#pragma unroll
            for (int rr = 0; rr < 4; ++rr) {
                const size_t idx = (c0 + rr) * NPX + n0 + ln;
                out[idx] = gm * acc[ct][rr] * iv + x[idx];
            }
        }
    }
}

// ---------------------------------------------------------------------------
// Combine: log-sum-exp merge of ns key-slice partials + gamma/residual.
// ---------------------------------------------------------------------------
__global__ __launch_bounds__(256) void combine_kernel(
    const unsigned short* __restrict__ opart,
    const float* __restrict__ mlm, const float* __restrict__ mll,
    const float* __restrict__ x, const float* __restrict__ gamma,
    float* __restrict__ out, int ns)
{
    const int idx = blockIdx.x * 256 + threadIdx.x;   // NB*CCH*512 threads
    const int bc  = idx >> 9;                          // b*CCH + c
    const int b   = bc / CCH;
    const int c   = bc - b * CCH;
    const int n0  = (idx & 511) * 8;

    float M[8];
#pragma unroll
    for (int i = 0; i < 8; ++i) M[i] = -INFINITY;
    for (int s = 0; s < ns; ++s) {
        const float* mp = mlm + ((size_t)(s * NB + b)) * NPX + n0;
#pragma unroll
        for (int i = 0; i < 8; ++i) M[i] = fmaxf(M[i], mp[i]);
    }

    float L[8], O[8];
#pragma unroll
    for (int i = 0; i < 8; ++i) { L[i] = 0.f; O[i] = 0.f; }
    for (int s = 0; s < ns; ++s) {
        const size_t sb = (size_t)(s * NB + b);
        const float* mp = mlm + sb * NPX + n0;
        const float* lp = mll + sb * NPX + n0;
        const bf16x8 v8 = *(const bf16x8*)(opart + (sb * CCH + c) * NPX + n0);
#pragma unroll
        for (int i = 0; i < 8; ++i) {
            const float wgt = __expf(mp[i] - M[i]);
            L[i] += wgt * lp[i];
            O[i] += wgt * bf2f((unsigned short)v8[i]);
        }
    }

    const float gm = gamma[0];
    const size_t xo = (size_t)bc * NPX + n0;
    float4 r0, r1;
    const float4 x0 = *(const float4*)(x + xo);
    const float4 x1 = *(const float4*)(x + xo + 4);
    r0.x = gm * O[0] / L[0] + x0.x;  r0.y = gm * O[1] / L[1] + x0.y;
    r0.z = gm * O[2] / L[2] + x0.z;  r0.w = gm * O[3] / L[3] + x0.w;
    r1.x = gm * O[4] / L[4] + x1.x;  r1.y = gm * O[5] / L[5] + x1.y;
    r1.z = gm * O[6] / L[6] + x1.z;  r1.w = gm * O[7] / L[7] + x1.w;
    *(float4*)(out + xo)     = r0;
    *(float4*)(out + xo + 4) = r1;
}

extern "C" void kernel_launch(void* const* d_in, const int* in_sizes, int n_in,
                              void* d_out, int out_size, void* d_ws, size_t ws_size,
                              hipStream_t stream)
{
    const float* x  = (const float*)d_in[0];
    const float* Wq = (const float*)d_in[1];
    const float* bq = (const float*)d_in[2];
    const float* Wk = (const float*)d_in[3];
    const float* bk = (const float*)d_in[4];
    const float* Wv = (const float*)d_in[5];
    const float* bv = (const float*)d_in[6];
    const float* gm = (const float*)d_in[7];
    float* out = (float*)d_out;
    unsigned short* ws = (unsigned short*)d_ws;

    const size_t qkvB   = (size_t)(2 * NB * NPX * 32 + NB * CCH * NPX) * 2;  // 10 MB
    const size_t partB  = (size_t)NB * CCH * NPX * 2;                        // 8 MB / slice
    const size_t mlB    = (size_t)2 * NB * NPX * 4;                          // 128 KB / slice
    int ns = 1;
    if      (ws_size >= qkvB + 4 * (partB + mlB)) ns = 4;
    else if (ws_size >= qkvB + 2 * (partB + mlB)) ns = 2;

    dim3 pgrid(NPX / 1024, 320 / 16, NB);
    proj_kernel<<<pgrid, 256, 0, stream>>>(x, Wq, bq, Wk, bk, Wv, bv, ws);

    const unsigned short* qT = ws;
    const unsigned short* kT = ws + (size_t)NB * NPX * 32;
    const unsigned short* vB = ws + (size_t)2 * NB * NPX * 32;

    // grid: NB * (NPX/QW) * ns wave-jobs, 4 waves per block
    const int ablocks = NB * (NPX / QW) * ns / 4;

    if (ns > 1) {
        unsigned short* opart = ws + (size_t)2 * NB * NPX * 32 + (size_t)NB * CCH * NPX;
        float* mlm = (float*)(opart + (size_t)ns * NB * CCH * NPX);
        float* mll = mlm + (size_t)ns * NB * NPX;

        attn_kernel<<<ablocks, 256, 0, stream>>>(qT, kT, vB, x, gm, out,
                                                 opart, mlm, mll, ns);

        const int cblocks = (NB * CCH * (NPX / 8)) / 256;
        combine_kernel<<<cblocks, 256, 0, stream>>>(opart, mlm, mll, x, gm, out, ns);
    } else {
        attn_kernel<<<ablocks, 256, 0, stream>>>(qT, kT, vB, x, gm, out,
                                                 nullptr, nullptr, nullptr, 1);
    }
}

// Round 9
// 142.792 us; speedup vs baseline: 2.3443x; 2.3443x over previous
//
#include <hip/hip_runtime.h>
#include <cstddef>
#include <cstdint>

#define CCH 256   // channels
#define DQK 32    // q/k channels
#define NPX 4096  // H*W
#define BQ2 128   // queries per block (8 waves x 16-query strips)
#define BM  64    // key tile per iteration
#define NB  4     // batch

typedef __attribute__((ext_vector_type(8))) short bf16x8;   // 8 bf16 = 4 VGPR (MFMA A/B frag)
typedef __attribute__((ext_vector_type(4))) float f32x4;    // MFMA C/D frag
typedef __attribute__((ext_vector_type(4))) unsigned int u32x4;

__device__ inline unsigned short f2bf(float f) {            // RNE float->bf16
    unsigned u = __builtin_bit_cast(unsigned, f);
    u += 0x7FFFu + ((u >> 16) & 1u);
    return (unsigned short)(u >> 16);
}
__device__ inline float bf2f(unsigned short h) {
    unsigned u = (unsigned)h << 16;
    return __builtin_bit_cast(float, u);
}

// ---------------------------------------------------------------------------
// Fused q/k/v 1x1-conv projection -> bf16 outputs in ws (unchanged, verified).
//   qT: [NB][NPX][32], kT: [NB][NPX][32], v: [NB][CCH][NPX]
// ---------------------------------------------------------------------------
__global__ __launch_bounds__(256) void proj_kernel(
    const float* __restrict__ x,
    const float* __restrict__ Wq, const float* __restrict__ bq,
    const float* __restrict__ Wk, const float* __restrict__ bk,
    const float* __restrict__ Wv, const float* __restrict__ bv,
    unsigned short* __restrict__ ws)
{
    const int tid = threadIdx.x;
    const int b   = blockIdx.z;
    const int o0  = blockIdx.y * 16;
    const int nb  = blockIdx.x * 1024 + tid * 4;

    const float* Wbase;
    const float* bbase;
    if (o0 < 32)      { Wbase = Wq + o0 * CCH;        bbase = bq + o0; }
    else if (o0 < 64) { Wbase = Wk + (o0 - 32) * CCH; bbase = bk + (o0 - 32); }
    else              { Wbase = Wv + (o0 - 64) * CCH; bbase = bv + (o0 - 64); }

    float4 acc[16];
#pragma unroll
    for (int ol = 0; ol < 16; ++ol) {
        float bb = bbase[ol];
        acc[ol] = make_float4(bb, bb, bb, bb);
    }

    const float* xp = x + ((size_t)b * CCH) * NPX + nb;
#pragma unroll 4
    for (int c = 0; c < CCH; ++c) {
        float4 x4 = *(const float4*)(xp + (size_t)c * NPX);
#pragma unroll
        for (int ol = 0; ol < 16; ++ol) {
            float w = Wbase[ol * CCH + c];
            acc[ol].x += w * x4.x;
            acc[ol].y += w * x4.y;
            acc[ol].z += w * x4.z;
            acc[ol].w += w * x4.w;
        }
    }

    if (o0 < 64) {
        unsigned short* dstT = ws + ((o0 < 32) ? (size_t)0 : (size_t)NB * NPX * 32);
        const int col0 = o0 & 16;
        unsigned short* base = dstT + ((size_t)b * NPX + nb) * 32 + col0;
#pragma unroll
        for (int p = 0; p < 4; ++p) {
            unsigned u[8];
#pragma unroll
            for (int h = 0; h < 8; ++h) {
                const float* a0 = (const float*)&acc[2 * h];
                const float* a1 = (const float*)&acc[2 * h + 1];
                u[h] = (unsigned)f2bf(a0[p]) | ((unsigned)f2bf(a1[p]) << 16);
            }
            u32x4* dp = (u32x4*)(base + (size_t)p * 32);
            dp[0] = (u32x4){u[0], u[1], u[2], u[3]};
            dp[1] = (u32x4){u[4], u[5], u[6], u[7]};
        }
    } else {
        unsigned short* vbase = ws + (size_t)2 * NB * NPX * 32;
        const int c0 = o0 - 64;
#pragma unroll
        for (int ol = 0; ol < 16; ++ol) {
            unsigned lo = (unsigned)f2bf(acc[ol].x) | ((unsigned)f2bf(acc[ol].y) << 16);
            unsigned hi = (unsigned)f2bf(acc[ol].z) | ((unsigned)f2bf(acc[ol].w) << 16);
            uint2* dp = (uint2*)(vbase + ((size_t)(b * CCH + c0 + ol)) * NPX + nb);
            *dp = make_uint2(lo, hi);
        }
    }
}

// ---------------------------------------------------------------------------
// Flash attention, BQ2=128 queries/block, 8 waves (512 thr).
// Wave w: softmax owner of query strip [w*16,w*16+16) (in-register m/l, R8
// style), PV owner of channel strip [w*32,w*32+32) x ALL 128 queries.
// P exchanged via shared LDS (XOR-swizzled rows), per-query scale in sc_lds.
// v is read once per block per key -> total v traffic 256MB; batch pinned to
// an XCD pair (bid&7) so per-batch v (2MB) stays L2-resident.
// ---------------------------------------------------------------------------
__global__ __launch_bounds__(512, 4) void attn_kernel(
    const unsigned short* __restrict__ qT, const unsigned short* __restrict__ kT,
    const unsigned short* __restrict__ vB, const float* __restrict__ x,
    const float* __restrict__ gamma, float* __restrict__ out,
    unsigned short* __restrict__ opart, float* __restrict__ mlm,
    float* __restrict__ mll, int ns)
{
    __shared__ __align__(16) unsigned short Pl[BQ2 * 64];   // 16KB, rows 128B, XOR swz
    __shared__ float sc_lds[BQ2];
    __shared__ float l_lds[BQ2];

    const int tid  = threadIdx.x;
    const int lane = tid & 63;
    const int w    = tid >> 6;       // wave 0..7
    const int ln   = lane & 15;
    const int g    = lane >> 4;      // 16-lane group 0..3
    const int bid  = blockIdx.x;

    const int b    = (bid & 7) >> 1;                        // batch -> XCD pair
    const int jb   = ((bid >> 3) << 1) | (bid & 1);         // job in batch
    const int tile = jb / ns;
    const int s    = jb - tile * ns;
    const int n0   = tile * BQ2;

    // softmax query owned by this lane: q = n0 + w*16 + ln
    const bf16x8 qf = *(const bf16x8*)(qT + ((size_t)b * NPX + n0 + w * 16 + ln) * 32 + g * 8);

    f32x4 acc[8][2];
#pragma unroll
    for (int qt = 0; qt < 8; ++qt) {
        acc[qt][0] = (f32x4){0.f, 0.f, 0.f, 0.f};
        acc[qt][1] = (f32x4){0.f, 0.f, 0.f, 0.f};
    }
    float mreg = -INFINITY, lreg = 0.f;

    const unsigned short* kTb = kT + (size_t)b * NPX * 32;
    const unsigned short* vb  = vB + ((size_t)b * CCH + w * 32) * NPX;
    const int kbase = s * (NPX / ns);
    const int iters = NPX / (ns * BM);
    const unsigned swz   = ((unsigned)ln & 7u) << 4;
    const unsigned myrow = (unsigned)(w * 16 + ln) * 128u;
    char* const plb = (char*)Pl;

    for (int mb = 0; mb < iters; ++mb) {
        const int m0 = kbase + mb * BM;

        // ---- E: 4 MFMA -> lane holds E[q = w*16+ln][k = 16*s4+4g+rr]
        f32x4 e[4];
#pragma unroll
        for (int s4 = 0; s4 < 4; ++s4) {
            const bf16x8 ka = *(const bf16x8*)(kTb + (size_t)(m0 + s4 * 16 + ln) * 32 + g * 8);
            e[s4] = __builtin_amdgcn_mfma_f32_16x16x32_bf16(
                        ka, qf, (f32x4){0.f, 0.f, 0.f, 0.f}, 0, 0, 0);
        }

        // ---- in-register online softmax (row reduce across g via shfl 16/32)
        float lm = -INFINITY;
#pragma unroll
        for (int s4 = 0; s4 < 4; ++s4)
#pragma unroll
            for (int rr = 0; rr < 4; ++rr) lm = fmaxf(lm, e[s4][rr]);
        lm = fmaxf(lm, __shfl_xor(lm, 16));
        lm = fmaxf(lm, __shfl_xor(lm, 32));
        const float mnew = fmaxf(mreg, lm);
        const float sc   = __expf(mreg - mnew);   // first iter: exp(-inf)=0
        float ps = 0.f;
#pragma unroll
        for (int s4 = 0; s4 < 4; ++s4)
#pragma unroll
            for (int rr = 0; rr < 4; ++rr) {
                const float p = __expf(e[s4][rr] - mnew);
                e[s4][rr] = p;
                ps += p;
            }
        ps += __shfl_xor(ps, 16);
        ps += __shfl_xor(ps, 32);
        lreg = lreg * sc + ps;
        mreg = mnew;

        // ---- P (bf16) -> shared LDS row (w*16+ln), XOR-swizzled; sc -> LDS
#pragma unroll
        for (int s4 = 0; s4 < 4; ++s4) {
            uint2 pk;
            pk.x = (unsigned)f2bf(e[s4][0]) | ((unsigned)f2bf(e[s4][1]) << 16);
            pk.y = (unsigned)f2bf(e[s4][2]) | ((unsigned)f2bf(e[s4][3]) << 16);
            *(uint2*)(plb + myrow + (((unsigned)(s4 * 32 + g * 8)) ^ swz)) = pk;
        }
        if (g == 0) sc_lds[w * 16 + ln] = sc;
        __syncthreads();   // B1: P + sc visible to all waves

        // ---- PV: rescale all acc columns, then 32 MFMA over channel strip
#pragma unroll
        for (int qt = 0; qt < 8; ++qt) {
            const float scq = sc_lds[qt * 16 + ln];
#pragma unroll
            for (int rr = 0; rr < 4; ++rr) {
                acc[qt][0][rr] *= scq;
                acc[qt][1][rr] *= scq;
            }
        }
        bf16x8 va[2][2];
#pragma unroll
        for (int ct = 0; ct < 2; ++ct) {
            const unsigned short* vrow = vb + (size_t)(ct * 16 + ln) * NPX + m0 + g * 8;
            va[ct][0] = *(const bf16x8*)(vrow);        // keys m0+8g+i
            va[ct][1] = *(const bf16x8*)(vrow + 32);   // keys m0+32+8g+i
        }
#pragma unroll
        for (int qt = 0; qt < 8; ++qt) {
            const unsigned rb = (unsigned)(qt * 16 + ln) * 128u;
            const bf16x8 pf0 = *(const bf16x8*)(plb + rb + (((unsigned)(g * 16))      ^ swz));
            const bf16x8 pf1 = *(const bf16x8*)(plb + rb + (((unsigned)(64 + g * 16)) ^ swz));
            acc[qt][0] = __builtin_amdgcn_mfma_f32_16x16x32_bf16(va[0][0], pf0, acc[qt][0], 0, 0, 0);
            acc[qt][0] = __builtin_amdgcn_mfma_f32_16x16x32_bf16(va[0][1], pf1, acc[qt][0], 0, 0, 0);
            acc[qt][1] = __builtin_amdgcn_mfma_f32_16x16x32_bf16(va[1][0], pf0, acc[qt][1], 0, 0, 0);
            acc[qt][1] = __builtin_amdgcn_mfma_f32_16x16x32_bf16(va[1][1], pf1, acc[qt][1], 0, 0, 0);
        }
        __syncthreads();   // B2: all waves done reading P before next overwrite
    }

    if (opart) {
        // partial epilogue: raw acc (bf16) + per-query m,l (owner wave writes)
        const size_t sb = (size_t)(s * NB + b);
#pragma unroll
        for (int qt = 0; qt < 8; ++qt)
#pragma unroll
            for (int ct = 0; ct < 2; ++ct) {
                const size_t c0 = sb * CCH + w * 32 + ct * 16 + g * 4;
#pragma unroll
                for (int rr = 0; rr < 4; ++rr)
                    opart[(c0 + rr) * NPX + n0 + qt * 16 + ln] = f2bf(acc[qt][ct][rr]);
            }
        if (g == 0) {
            mlm[sb * NPX + n0 + w * 16 + ln] = mreg;
            mll[sb * NPX + n0 + w * 16 + ln] = lreg;
        }
    } else {
        // direct epilogue (ns==1): need per-query l for ALL queries -> LDS
        if (g == 0) l_lds[w * 16 + ln] = lreg;
        __syncthreads();
        const float gm = gamma[0];
#pragma unroll
        for (int qt = 0; qt < 8; ++qt) {
            const float iv = 1.f / l_lds[qt * 16 + ln];
#pragma unroll
            for (int ct = 0; ct < 2; ++ct) {
                const size_t c0 = (size_t)b * CCH + w * 32 + ct * 16 + g * 4;
#pragma unroll
                for (int rr = 0; rr < 4; ++rr) {
                    const size_t idx = (c0 + rr) * NPX + n0 + qt * 16 + ln;
                    out[idx] = gm * acc[qt][ct][rr] * iv + x[idx];
                }
            }
        }
    }
}

// ---------------------------------------------------------------------------
// Combine: log-sum-exp merge of ns key-slice partials + gamma/residual.
// ---------------------------------------------------------------------------
__global__ __launch_bounds__(256) void combine_kernel(
    const unsigned short* __restrict__ opart,
    const float* __restrict__ mlm, const float* __restrict__ mll,
    const float* __restrict__ x, const float* __restrict__ gamma,
    float* __restrict__ out, int ns)
{
    const int idx = blockIdx.x * 256 + threadIdx.x;   // NB*CCH*512 threads
    const int bc  = idx >> 9;                          // b*CCH + c
    const int b   = bc / CCH;
    const int c   = bc - b * CCH;
    const int n0  = (idx & 511) * 8;

    float M[8];
#pragma unroll
    for (int i = 0; i < 8; ++i) M[i] = -INFINITY;
    for (int s = 0; s < ns; ++s) {
        const float* mp = mlm + ((size_t)(s * NB + b)) * NPX + n0;
#pragma unroll
        for (int i = 0; i < 8; ++i) M[i] = fmaxf(M[i], mp[i]);
    }

    float L[8], O[8];
#pragma unroll
    for (int i = 0; i < 8; ++i) { L[i] = 0.f; O[i] = 0.f; }
    for (int s = 0; s < ns; ++s) {
        const size_t sb = (size_t)(s * NB + b);
        const float* mp = mlm + sb * NPX + n0;
        const float* lp = mll + sb * NPX + n0;
        const bf16x8 v8 = *(const bf16x8*)(opart + (sb * CCH + c) * NPX + n0);
#pragma unroll
        for (int i = 0; i < 8; ++i) {
            const float wgt = __expf(mp[i] - M[i]);
            L[i] += wgt * lp[i];
            O[i] += wgt * bf2f((unsigned short)v8[i]);
        }
    }

    const float gm = gamma[0];
    const size_t xo = (size_t)bc * NPX + n0;
    float4 r0, r1;
    const float4 x0 = *(const float4*)(x + xo);
    const float4 x1 = *(const float4*)(x + xo + 4);
    r0.x = gm * O[0] / L[0] + x0.x;  r0.y = gm * O[1] / L[1] + x0.y;
    r0.z = gm * O[2] / L[2] + x0.z;  r0.w = gm * O[3] / L[3] + x0.w;
    r1.x = gm * O[4] / L[4] + x1.x;  r1.y = gm * O[5] / L[5] + x1.y;
    r1.z = gm * O[6] / L[6] + x1.z;  r1.w = gm * O[7] / L[7] + x1.w;
    *(float4*)(out + xo)     = r0;
    *(float4*)(out + xo + 4) = r1;
}

extern "C" void kernel_launch(void* const* d_in, const int* in_sizes, int n_in,
                              void* d_out, int out_size, void* d_ws, size_t ws_size,
                              hipStream_t stream)
{
    const float* x  = (const float*)d_in[0];
    const float* Wq = (const float*)d_in[1];
    const float* bq = (const float*)d_in[2];
    const float* Wk = (const float*)d_in[3];
    const float* bk = (const float*)d_in[4];
    const float* Wv = (const float*)d_in[5];
    const float* bv = (const float*)d_in[6];
    const float* gm = (const float*)d_in[7];
    float* out = (float*)d_out;
    unsigned short* ws = (unsigned short*)d_ws;

    const size_t qkvB   = (size_t)(2 * NB * NPX * 32 + NB * CCH * NPX) * 2;  // 10 MB
    const size_t partB  = (size_t)NB * CCH * NPX * 2;                        // 8 MB / slice
    const size_t mlB    = (size_t)2 * NB * NPX * 4;                          // 128 KB / slice
    int ns = 1;
    if      (ws_size >= qkvB + 4 * (partB + mlB)) ns = 4;
    else if (ws_size >= qkvB + 2 * (partB + mlB)) ns = 2;

    dim3 pgrid(NPX / 1024, 320 / 16, NB);
    proj_kernel<<<pgrid, 256, 0, stream>>>(x, Wq, bq, Wk, bk, Wv, bv, ws);

    const unsigned short* qT = ws;
    const unsigned short* kT = ws + (size_t)NB * NPX * 32;
    const unsigned short* vB = ws + (size_t)2 * NB * NPX * 32;

    // grid: NB batches x (NPX/BQ2) tiles x ns slices, one job per block
    const int ablocks = NB * (NPX / BQ2) * ns;

    if (ns > 1) {
        unsigned short* opart = ws + (size_t)2 * NB * NPX * 32 + (size_t)NB * CCH * NPX;
        float* mlm = (float*)(opart + (size_t)ns * NB * CCH * NPX);
        float* mll = mlm + (size_t)ns * NB * NPX;

        attn_kernel<<<ablocks, 512, 0, stream>>>(qT, kT, vB, x, gm, out,
                                                 opart, mlm, mll, ns);

        const int cblocks = (NB * CCH * (NPX / 8)) / 256;
        combine_kernel<<<cblocks, 256, 0, stream>>>(opart, mlm, mll, x, gm, out, ns);
    } else {
        attn_kernel<<<ablocks, 512, 0, stream>>>(qT, kT, vB, x, gm, out,
                                                 nullptr, nullptr, nullptr, 1);
    }
}

// Round 10
// 136.555 us; speedup vs baseline: 2.4514x; 1.0457x over previous
//
#include <hip/hip_runtime.h>
#include <cstddef>
#include <cstdint>

#define CCH 256   // channels
#define DQK 32    // q/k channels
#define NPX 4096  // H*W
#define BQ2 128   // queries per block (8 waves x 16-query strips)
#define BM  64    // key tile per iteration
#define NB  4     // batch

typedef __attribute__((ext_vector_type(8))) short bf16x8;   // 8 bf16 = 4 VGPR (MFMA A/B frag)
typedef __attribute__((ext_vector_type(4))) float f32x4;    // MFMA C/D frag
typedef __attribute__((ext_vector_type(4))) unsigned int u32x4;

__device__ inline unsigned short f2bf(float f) {            // RNE float->bf16
    unsigned u = __builtin_bit_cast(unsigned, f);
    u += 0x7FFFu + ((u >> 16) & 1u);
    return (unsigned short)(u >> 16);
}
__device__ inline float bf2f(unsigned short h) {
    unsigned u = (unsigned)h << 16;
    return __builtin_bit_cast(float, u);
}

// ---------------------------------------------------------------------------
// Fused q/k/v 1x1-conv projection -> bf16 outputs in ws.
//   qT: [NB][NPX][32], kT: [NB][NPX][32], v: [NB][CCH][NPX]
// R10: 1 px/thread, 256 px/block, 1280 blocks (64 slabs x 20 oc-groups).
// Pixel-slab (256KB of x) pinned to an XCD via bid&7 so the 20 oc-group
// re-reads hit that XCD's L2. 5 blocks/CU -> 20 waves/CU for latency hiding.
// ---------------------------------------------------------------------------
__global__ __launch_bounds__(256) void proj_kernel(
    const float* __restrict__ x,
    const float* __restrict__ Wq, const float* __restrict__ bq,
    const float* __restrict__ Wk, const float* __restrict__ bk,
    const float* __restrict__ Wv, const float* __restrict__ bv,
    unsigned short* __restrict__ ws)
{
    const int tid  = threadIdx.x;
    const int bid  = blockIdx.x;
    const int xcd  = bid & 7;
    const int rem  = bid >> 3;           // 0..159
    const int sidx = rem / 20;           // slab index within XCD 0..7
    const int ocg  = rem % 20;           // oc-group 0..19
    const int slab = xcd + 8 * sidx;     // 0..63
    const int b    = slab >> 4;          // batch
    const int px   = slab & 15;          // pixel slab in batch
    const int o0   = ocg * 16;
    const int n    = px * 256 + tid;     // this thread's pixel

    const float* Wbase;
    const float* bbase;
    if (o0 < 32)      { Wbase = Wq + o0 * CCH;        bbase = bq + o0; }
    else if (o0 < 64) { Wbase = Wk + (o0 - 32) * CCH; bbase = bk + (o0 - 32); }
    else              { Wbase = Wv + (o0 - 64) * CCH; bbase = bv + (o0 - 64); }

    float acc[16];
#pragma unroll
    for (int ol = 0; ol < 16; ++ol) acc[ol] = bbase[ol];

    const float* xp = x + ((size_t)b * CCH) * NPX + n;
#pragma unroll 4
    for (int c = 0; c < CCH; ++c) {
        const float xv = xp[(size_t)c * NPX];
#pragma unroll
        for (int ol = 0; ol < 16; ++ol)
            acc[ol] += Wbase[ol * CCH + c] * xv;
    }

    if (o0 < 64) {
        // qT/kT[n][32]: thread owns 16 contiguous d at col0
        unsigned short* dstT = ws + ((o0 < 32) ? (size_t)0 : (size_t)NB * NPX * 32);
        const int col0 = o0 & 16;
        unsigned u[8];
#pragma unroll
        for (int h = 0; h < 8; ++h)
            u[h] = (unsigned)f2bf(acc[2 * h]) | ((unsigned)f2bf(acc[2 * h + 1]) << 16);
        u32x4* dp = (u32x4*)(dstT + ((size_t)b * NPX + n) * 32 + col0);
        dp[0] = (u32x4){u[0], u[1], u[2], u[3]};
        dp[1] = (u32x4){u[4], u[5], u[6], u[7]};
    } else {
        unsigned short* vbase = ws + (size_t)2 * NB * NPX * 32;
        const int c0 = o0 - 64;
#pragma unroll
        for (int ol = 0; ol < 16; ++ol)
            vbase[((size_t)(b * CCH + c0 + ol)) * NPX + n] = f2bf(acc[ol]);
    }
}

// ---------------------------------------------------------------------------
// Flash attention, BQ2=128 queries/block, 8 waves (512 thr). (unchanged R9)
// ---------------------------------------------------------------------------
__global__ __launch_bounds__(512, 4) void attn_kernel(
    const unsigned short* __restrict__ qT, const unsigned short* __restrict__ kT,
    const unsigned short* __restrict__ vB, const float* __restrict__ x,
    const float* __restrict__ gamma, float* __restrict__ out,
    unsigned short* __restrict__ opart, float* __restrict__ mlm,
    float* __restrict__ mll, int ns)
{
    __shared__ __align__(16) unsigned short Pl[BQ2 * 64];   // 16KB, rows 128B, XOR swz
    __shared__ float sc_lds[BQ2];
    __shared__ float l_lds[BQ2];

    const int tid  = threadIdx.x;
    const int lane = tid & 63;
    const int w    = tid >> 6;       // wave 0..7
    const int ln   = lane & 15;
    const int g    = lane >> 4;      // 16-lane group 0..3
    const int bid  = blockIdx.x;

    const int b    = (bid & 7) >> 1;                        // batch -> XCD pair
    const int jb   = ((bid >> 3) << 1) | (bid & 1);         // job in batch
    const int tile = jb / ns;
    const int s    = jb - tile * ns;
    const int n0   = tile * BQ2;

    // softmax query owned by this lane: q = n0 + w*16 + ln
    const bf16x8 qf = *(const bf16x8*)(qT + ((size_t)b * NPX + n0 + w * 16 + ln) * 32 + g * 8);

    f32x4 acc[8][2];
#pragma unroll
    for (int qt = 0; qt < 8; ++qt) {
        acc[qt][0] = (f32x4){0.f, 0.f, 0.f, 0.f};
        acc[qt][1] = (f32x4){0.f, 0.f, 0.f, 0.f};
    }
    float mreg = -INFINITY, lreg = 0.f;

    const unsigned short* kTb = kT + (size_t)b * NPX * 32;
    const unsigned short* vb  = vB + ((size_t)b * CCH + w * 32) * NPX;
    const int kbase = s * (NPX / ns);
    const int iters = NPX / (ns * BM);
    const unsigned swz   = ((unsigned)ln & 7u) << 4;
    const unsigned myrow = (unsigned)(w * 16 + ln) * 128u;
    char* const plb = (char*)Pl;

    for (int mb = 0; mb < iters; ++mb) {
        const int m0 = kbase + mb * BM;

        // ---- E: 4 MFMA -> lane holds E[q = w*16+ln][k = 16*s4+4g+rr]
        f32x4 e[4];
#pragma unroll
        for (int s4 = 0; s4 < 4; ++s4) {
            const bf16x8 ka = *(const bf16x8*)(kTb + (size_t)(m0 + s4 * 16 + ln) * 32 + g * 8);
            e[s4] = __builtin_amdgcn_mfma_f32_16x16x32_bf16(
                        ka, qf, (f32x4){0.f, 0.f, 0.f, 0.f}, 0, 0, 0);
        }

        // ---- in-register online softmax (row reduce across g via shfl 16/32)
        float lm = -INFINITY;
#pragma unroll
        for (int s4 = 0; s4 < 4; ++s4)
#pragma unroll
            for (int rr = 0; rr < 4; ++rr) lm = fmaxf(lm, e[s4][rr]);
        lm = fmaxf(lm, __shfl_xor(lm, 16));
        lm = fmaxf(lm, __shfl_xor(lm, 32));
        const float mnew = fmaxf(mreg, lm);
        const float sc   = __expf(mreg - mnew);   // first iter: exp(-inf)=0
        float ps = 0.f;
#pragma unroll
        for (int s4 = 0; s4 < 4; ++s4)
#pragma unroll
            for (int rr = 0; rr < 4; ++rr) {
                const float p = __expf(e[s4][rr] - mnew);
                e[s4][rr] = p;
                ps += p;
            }
        ps += __shfl_xor(ps, 16);
        ps += __shfl_xor(ps, 32);
        lreg = lreg * sc + ps;
        mreg = mnew;

        // ---- P (bf16) -> shared LDS row (w*16+ln), XOR-swizzled; sc -> LDS
#pragma unroll
        for (int s4 = 0; s4 < 4; ++s4) {
            uint2 pk;
            pk.x = (unsigned)f2bf(e[s4][0]) | ((unsigned)f2bf(e[s4][1]) << 16);
            pk.y = (unsigned)f2bf(e[s4][2]) | ((unsigned)f2bf(e[s4][3]) << 16);
            *(uint2*)(plb + myrow + (((unsigned)(s4 * 32 + g * 8)) ^ swz)) = pk;
        }
        if (g == 0) sc_lds[w * 16 + ln] = sc;
        __syncthreads();   // B1: P + sc visible to all waves

        // ---- PV: rescale all acc columns, then 32 MFMA over channel strip
#pragma unroll
        for (int qt = 0; qt < 8; ++qt) {
            const float scq = sc_lds[qt * 16 + ln];
#pragma unroll
            for (int rr = 0; rr < 4; ++rr) {
                acc[qt][0][rr] *= scq;
                acc[qt][1][rr] *= scq;
            }
        }
        bf16x8 va[2][2];
#pragma unroll
        for (int ct = 0; ct < 2; ++ct) {
            const unsigned short* vrow = vb + (size_t)(ct * 16 + ln) * NPX + m0 + g * 8;
            va[ct][0] = *(const bf16x8*)(vrow);        // keys m0+8g+i
            va[ct][1] = *(const bf16x8*)(vrow + 32);   // keys m0+32+8g+i
        }
#pragma unroll
        for (int qt = 0; qt < 8; ++qt) {
            const unsigned rb = (unsigned)(qt * 16 + ln) * 128u;
            const bf16x8 pf0 = *(const bf16x8*)(plb + rb + (((unsigned)(g * 16))      ^ swz));
            const bf16x8 pf1 = *(const bf16x8*)(plb + rb + (((unsigned)(64 + g * 16)) ^ swz));
            acc[qt][0] = __builtin_amdgcn_mfma_f32_16x16x32_bf16(va[0][0], pf0, acc[qt][0], 0, 0, 0);
            acc[qt][0] = __builtin_amdgcn_mfma_f32_16x16x32_bf16(va[0][1], pf1, acc[qt][0], 0, 0, 0);
            acc[qt][1] = __builtin_amdgcn_mfma_f32_16x16x32_bf16(va[1][0], pf0, acc[qt][1], 0, 0, 0);
            acc[qt][1] = __builtin_amdgcn_mfma_f32_16x16x32_bf16(va[1][1], pf1, acc[qt][1], 0, 0, 0);
        }
        __syncthreads();   // B2: all waves done reading P before next overwrite
    }

    if (opart) {
        // partial epilogue: raw acc (bf16) + per-query m,l (owner wave writes)
        const size_t sb = (size_t)(s * NB + b);
#pragma unroll
        for (int qt = 0; qt < 8; ++qt)
#pragma unroll
            for (int ct = 0; ct < 2; ++ct) {
                const size_t c0 = sb * CCH + w * 32 + ct * 16 + g * 4;
#pragma unroll
                for (int rr = 0; rr < 4; ++rr)
                    opart[(c0 + rr) * NPX + n0 + qt * 16 + ln] = f2bf(acc[qt][ct][rr]);
            }
        if (g == 0) {
            mlm[sb * NPX + n0 + w * 16 + ln] = mreg;
            mll[sb * NPX + n0 + w * 16 + ln] = lreg;
        }
    } else {
        // direct epilogue (ns==1): need per-query l for ALL queries -> LDS
        if (g == 0) l_lds[w * 16 + ln] = lreg;
        __syncthreads();
        const float gm = gamma[0];
#pragma unroll
        for (int qt = 0; qt < 8; ++qt) {
            const float iv = 1.f / l_lds[qt * 16 + ln];
#pragma unroll
            for (int ct = 0; ct < 2; ++ct) {
                const size_t c0 = (size_t)b * CCH + w * 32 + ct * 16 + g * 4;
#pragma unroll
                for (int rr = 0; rr < 4; ++rr) {
                    const size_t idx = (c0 + rr) * NPX + n0 + qt * 16 + ln;
                    out[idx] = gm * acc[qt][ct][rr] * iv + x[idx];
                }
            }
        }
    }
}

// ---------------------------------------------------------------------------
// Combine: log-sum-exp merge of ns key-slice partials + gamma/residual.
// ---------------------------------------------------------------------------
__global__ __launch_bounds__(256) void combine_kernel(
    const unsigned short* __restrict__ opart,
    const float* __restrict__ mlm, const float* __restrict__ mll,
    const float* __restrict__ x, const float* __restrict__ gamma,
    float* __restrict__ out, int ns)
{
    const int idx = blockIdx.x * 256 + threadIdx.x;   // NB*CCH*512 threads
    const int bc  = idx >> 9;                          // b*CCH + c
    const int b   = bc / CCH;
    const int c   = bc - b * CCH;
    const int n0  = (idx & 511) * 8;

    float M[8];
#pragma unroll
    for (int i = 0; i < 8; ++i) M[i] = -INFINITY;
    for (int s = 0; s < ns; ++s) {
        const float* mp = mlm + ((size_t)(s * NB + b)) * NPX + n0;
#pragma unroll
        for (int i = 0; i < 8; ++i) M[i] = fmaxf(M[i], mp[i]);
    }

    float L[8], O[8];
#pragma unroll
    for (int i = 0; i < 8; ++i) { L[i] = 0.f; O[i] = 0.f; }
    for (int s = 0; s < ns; ++s) {
        const size_t sb = (size_t)(s * NB + b);
        const float* mp = mlm + sb * NPX + n0;
        const float* lp = mll + sb * NPX + n0;
        const bf16x8 v8 = *(const bf16x8*)(opart + (sb * CCH + c) * NPX + n0);
#pragma unroll
        for (int i = 0; i < 8; ++i) {
            const float wgt = __expf(mp[i] - M[i]);
            L[i] += wgt * lp[i];
            O[i] += wgt * bf2f((unsigned short)v8[i]);
        }
    }

    const float gm = gamma[0];
    const size_t xo = (size_t)bc * NPX + n0;
    float4 r0, r1;
    const float4 x0 = *(const float4*)(x + xo);
    const float4 x1 = *(const float4*)(x + xo + 4);
    r0.x = gm * O[0] / L[0] + x0.x;  r0.y = gm * O[1] / L[1] + x0.y;
    r0.z = gm * O[2] / L[2] + x0.z;  r0.w = gm * O[3] / L[3] + x0.w;
    r1.x = gm * O[4] / L[4] + x1.x;  r1.y = gm * O[5] / L[5] + x1.y;
    r1.z = gm * O[6] / L[6] + x1.z;  r1.w = gm * O[7] / L[7] + x1.w;
    *(float4*)(out + xo)     = r0;
    *(float4*)(out + xo + 4) = r1;
}

extern "C" void kernel_launch(void* const* d_in, const int* in_sizes, int n_in,
                              void* d_out, int out_size, void* d_ws, size_t ws_size,
                              hipStream_t stream)
{
    const float* x  = (const float*)d_in[0];
    const float* Wq = (const float*)d_in[1];
    const float* bq = (const float*)d_in[2];
    const float* Wk = (const float*)d_in[3];
    const float* bk = (const float*)d_in[4];
    const float* Wv = (const float*)d_in[5];
    const float* bv = (const float*)d_in[6];
    const float* gm = (const float*)d_in[7];
    float* out = (float*)d_out;
    unsigned short* ws = (unsigned short*)d_ws;

    const size_t qkvB   = (size_t)(2 * NB * NPX * 32 + NB * CCH * NPX) * 2;  // 10 MB
    const size_t partB  = (size_t)NB * CCH * NPX * 2;                        // 8 MB / slice
    const size_t mlB    = (size_t)2 * NB * NPX * 4;                          // 128 KB / slice
    int ns = 1;
    if      (ws_size >= qkvB + 4 * (partB + mlB)) ns = 4;
    else if (ws_size >= qkvB + 2 * (partB + mlB)) ns = 2;

    // proj: 64 pixel-slabs (NB*16) x 20 oc-groups, slab pinned to XCD
    proj_kernel<<<1280, 256, 0, stream>>>(x, Wq, bq, Wk, bk, Wv, bv, ws);

    const unsigned short* qT = ws;
    const unsigned short* kT = ws + (size_t)NB * NPX * 32;
    const unsigned short* vB = ws + (size_t)2 * NB * NPX * 32;

    // grid: NB batches x (NPX/BQ2) tiles x ns slices, one job per block
    const int ablocks = NB * (NPX / BQ2) * ns;

    if (ns > 1) {
        unsigned short* opart = ws + (size_t)2 * NB * NPX * 32 + (size_t)NB * CCH * NPX;
        float* mlm = (float*)(opart + (size_t)ns * NB * CCH * NPX);
        float* mll = mlm + (size_t)ns * NB * NPX;

        attn_kernel<<<ablocks, 512, 0, stream>>>(qT, kT, vB, x, gm, out,
                                                 opart, mlm, mll, ns);

        const int cblocks = (NB * CCH * (NPX / 8)) / 256;
        combine_kernel<<<cblocks, 256, 0, stream>>>(opart, mlm, mll, x, gm, out, ns);
    } else {
        attn_kernel<<<ablocks, 512, 0, stream>>>(qT, kT, vB, x, gm, out,
                                                 nullptr, nullptr, nullptr, 1);
    }
}